// Round 1
// baseline (320.800 us; speedup 1.0000x reference)
//
#include <hip/hip_runtime.h>
#include <math.h>

// Problem constants (from reference setup_inputs)
#define Bb 8
#define Cc 24
#define Hh 320
#define Ww 640
#define HWp (Hh * Ww)        // 204800
#define NPIX (Bb * HWp)      // 1638400
#define PIX_PER_THREAD 4

// Each thread handles 4 consecutive pixels (same b, contiguous w) so every
// global load is a coalesced float4 (16 B/lane across the wave).
//
// v2: batch ALL 24 channel loads into registers before the top-2 scan.
// v1 had VGPR_Count=20 -> compiler serialized to ~1 outstanding load/wave
// (load, vmcnt(0), compare, repeat) -> latency-bound at 1.5 TB/s (18% peak).
// 24 outstanding global_load_dwordx4 per wave (~24 KB in flight) trades
// occupancy (VGPR ~120, ~16 waves/CU) for memory-level parallelism.
__global__ __launch_bounds__(256) void sparse_regression_kernel(
    const float* __restrict__ cost,
    const float* __restrict__ disp,
    float* __restrict__ pred,   // [B,H,W]   = NPIX floats
    float* __restrict__ prob)   // [B,2,H,W] = 2*NPIX floats
{
    const int t  = blockIdx.x * blockDim.x + threadIdx.x;
    const int p0 = t * PIX_PER_THREAD;
    if (p0 >= NPIX) return;

    const int b = p0 / HWp;          // 4-pixel groups never straddle b (HW%4==0)
    const int q = p0 - b * HWp;      // h*W + w

    const size_t base = (size_t)b * Cc * HWp + q;
    const float* cbase = cost + base;
    const float* dbase = disp + base;

    // ---- Issue all 24 channel loads up front (fully static indexing after
    // unroll -> stays in VGPRs, rule: no runtime-indexed arrays). ----
    float4 v[Cc];
#pragma unroll
    for (int c = 0; c < Cc; ++c) {
        v[c] = *(const float4*)(cbase + (size_t)c * HWp);
    }

    float max1[PIX_PER_THREAD], max2[PIX_PER_THREAD];
    int   idx1[PIX_PER_THREAD], idx2[PIX_PER_THREAD];
#pragma unroll
    for (int j = 0; j < PIX_PER_THREAD; ++j) {
        max1[j] = -INFINITY; max2[j] = -INFINITY;
        idx1[j] = 0;         idx2[j] = 0;
    }

    // Streaming top-2 over channels (register-resident). Strict '>' while
    // scanning c ascending reproduces lax.top_k's lower-index-wins ties.
#pragma unroll
    for (int c = 0; c < Cc; ++c) {
        const float vv[4] = {v[c].x, v[c].y, v[c].z, v[c].w};
#pragma unroll
        for (int j = 0; j < PIX_PER_THREAD; ++j) {
            const float val = vv[j];
            const bool gt1 = val > max1[j];
            const bool gt2 = val > max2[j];
            max2[j] = gt1 ? max1[j] : (gt2 ? val : max2[j]);
            idx2[j] = gt1 ? idx1[j] : (gt2 ? c   : idx2[j]);
            max1[j] = gt1 ? val     : max1[j];
            idx1[j] = gt1 ? c       : idx1[j];
        }
    }

    // ---- Gather the two selected disparity samples: issue all 8 loads
    // before any use so they overlap (data-dependent addresses, ~2/24 of
    // the disp planes touched; mostly L2/L3 hits per FETCH_SIZE). ----
    float d1[PIX_PER_THREAD], d2[PIX_PER_THREAD];
#pragma unroll
    for (int j = 0; j < PIX_PER_THREAD; ++j) {
        d1[j] = dbase[(size_t)idx1[j] * HWp + j];
        d2[j] = dbase[(size_t)idx2[j] * HWp + j];
    }

    float predo[PIX_PER_THREAD], p1o[PIX_PER_THREAD], p2o[PIX_PER_THREAD];
#pragma unroll
    for (int j = 0; j < PIX_PER_THREAD; ++j) {
        // softmax over {max1, max2}: p1 = 1/(1+exp(m2-m1)), m2-m1 <= 0
        const float e  = __expf(max2[j] - max1[j]);
        const float p1 = 1.0f / (1.0f + e);
        const float p2 = 1.0f - p1;
        predo[j] = d1[j] * p1 + d2[j] * p2;
        p1o[j] = p1;
        p2o[j] = p2;
    }

    // Coalesced float4 stores.
    *(float4*)(pred + p0) = make_float4(predo[0], predo[1], predo[2], predo[3]);
    float* pb = prob + (size_t)b * 2 * HWp + q;
    *(float4*)(pb)       = make_float4(p1o[0], p1o[1], p1o[2], p1o[3]);
    *(float4*)(pb + HWp) = make_float4(p2o[0], p2o[1], p2o[2], p2o[3]);
}

extern "C" void kernel_launch(void* const* d_in, const int* in_sizes, int n_in,
                              void* d_out, int out_size, void* d_ws, size_t ws_size,
                              hipStream_t stream) {
    const float* cost = (const float*)d_in[0];
    const float* disp = (const float*)d_in[1];
    float* pred = (float*)d_out;          // first NPIX floats
    float* prob = (float*)d_out + NPIX;   // next 2*NPIX floats

    const int threads = NPIX / PIX_PER_THREAD;   // 409600
    const int block = 256;
    const int grid = (threads + block - 1) / block;  // 1600
    sparse_regression_kernel<<<grid, block, 0, stream>>>(cost, disp, pred, prob);
}

// Round 2
// 319.009 us; speedup vs baseline: 1.0056x; 1.0056x over previous
//
#include <hip/hip_runtime.h>
#include <math.h>

// Problem constants (from reference setup_inputs)
#define Bb 8
#define Cc 24
#define Hh 320
#define Ww 640
#define HWp (Hh * Ww)        // 204800
#define NPIX (Bb * HWp)      // 1638400
#define PIX_PER_THREAD 4

// Each thread handles 4 consecutive pixels (same b, contiguous w) so every
// global load is a coalesced float4 (16 B/lane across the wave).
//
// v3: v2 tried to batch all 24 channel loads in registers, but the compiler
// re-sank them into the consume loop (VGPR_Count stayed 36 -> ~4 loads in
// flight -> unchanged 117 us, 1.5 TB/s, latency-bound). This version pins
// the schedule with sched_barrier(0): all 24 global_load_dwordx4 must issue
// before the scan reads v[0]. Expect VGPR ~120 and counted vmcnt(23..0)
// waits (T4 pattern) instead of serial load->vmcnt(0)->consume.
__global__ __launch_bounds__(256) void sparse_regression_kernel(
    const float* __restrict__ cost,
    const float* __restrict__ disp,
    float* __restrict__ pred,   // [B,H,W]   = NPIX floats
    float* __restrict__ prob)   // [B,2,H,W] = 2*NPIX floats
{
    const int t  = blockIdx.x * blockDim.x + threadIdx.x;
    const int p0 = t * PIX_PER_THREAD;
    if (p0 >= NPIX) return;

    const int b = p0 / HWp;          // 4-pixel groups never straddle b (HW%4==0)
    const int q = p0 - b * HWp;      // h*W + w

    const size_t base = (size_t)b * Cc * HWp + q;
    const float* cbase = cost + base;
    const float* dbase = disp + base;

    // ---- Issue ALL 24 channel loads. The sched_barrier(0) below prevents
    // the machine scheduler from sinking any of them past it, so all 24
    // stay in flight (~96 data VGPRs, ~24 KB outstanding per wave). ----
    float4 v[Cc];
#pragma unroll
    for (int c = 0; c < Cc; ++c) {
        v[c] = *(const float4*)(cbase + (size_t)c * HWp);
    }
    __builtin_amdgcn_sched_barrier(0);   // no instruction may cross

    float max1[PIX_PER_THREAD], max2[PIX_PER_THREAD];
    int   idx1[PIX_PER_THREAD], idx2[PIX_PER_THREAD];
#pragma unroll
    for (int j = 0; j < PIX_PER_THREAD; ++j) {
        max1[j] = -INFINITY; max2[j] = -INFINITY;
        idx1[j] = 0;         idx2[j] = 0;
    }

    // Streaming top-2 over channels, consuming in load order so the
    // waitcnt pass emits counted vmcnt(23), vmcnt(22), ... waits.
    // Strict '>' scanning c ascending reproduces lax.top_k tie-breaking.
#pragma unroll
    for (int c = 0; c < Cc; ++c) {
        const float vv[4] = {v[c].x, v[c].y, v[c].z, v[c].w};
#pragma unroll
        for (int j = 0; j < PIX_PER_THREAD; ++j) {
            const float val = vv[j];
            const bool gt1 = val > max1[j];
            const bool gt2 = val > max2[j];
            max2[j] = gt1 ? max1[j] : (gt2 ? val : max2[j]);
            idx2[j] = gt1 ? idx1[j] : (gt2 ? c   : idx2[j]);
            max1[j] = gt1 ? val     : max1[j];
            idx1[j] = gt1 ? c       : idx1[j];
        }
    }

    // ---- Gather the two selected disparity samples: issue all 8 loads
    // before any use so they overlap (data-dependent addresses; mostly
    // L2/L3 hits per FETCH_SIZE). ----
    float d1[PIX_PER_THREAD], d2[PIX_PER_THREAD];
#pragma unroll
    for (int j = 0; j < PIX_PER_THREAD; ++j) {
        d1[j] = dbase[(size_t)idx1[j] * HWp + j];
        d2[j] = dbase[(size_t)idx2[j] * HWp + j];
    }

    float predo[PIX_PER_THREAD], p1o[PIX_PER_THREAD], p2o[PIX_PER_THREAD];
#pragma unroll
    for (int j = 0; j < PIX_PER_THREAD; ++j) {
        // softmax over {max1, max2}: p1 = 1/(1+exp(m2-m1)), m2-m1 <= 0
        const float e  = __expf(max2[j] - max1[j]);
        const float p1 = 1.0f / (1.0f + e);
        const float p2 = 1.0f - p1;
        predo[j] = d1[j] * p1 + d2[j] * p2;
        p1o[j] = p1;
        p2o[j] = p2;
    }

    // Coalesced float4 stores.
    *(float4*)(pred + p0) = make_float4(predo[0], predo[1], predo[2], predo[3]);
    float* pb = prob + (size_t)b * 2 * HWp + q;
    *(float4*)(pb)       = make_float4(p1o[0], p1o[1], p1o[2], p1o[3]);
    *(float4*)(pb + HWp) = make_float4(p2o[0], p2o[1], p2o[2], p2o[3]);
}

extern "C" void kernel_launch(void* const* d_in, const int* in_sizes, int n_in,
                              void* d_out, int out_size, void* d_ws, size_t ws_size,
                              hipStream_t stream) {
    const float* cost = (const float*)d_in[0];
    const float* disp = (const float*)d_in[1];
    float* pred = (float*)d_out;          // first NPIX floats
    float* prob = (float*)d_out + NPIX;   // next 2*NPIX floats

    const int threads = NPIX / PIX_PER_THREAD;   // 409600
    const int block = 256;
    const int grid = (threads + block - 1) / block;  // 1600
    sparse_regression_kernel<<<grid, block, 0, stream>>>(cost, disp, pred, prob);
}

// Round 3
// 315.588 us; speedup vs baseline: 1.0165x; 1.0108x over previous
//
#include <hip/hip_runtime.h>
#include <math.h>

// Problem constants (from reference setup_inputs)
#define Bb 8
#define Cc 24
#define Hh 320
#define Ww 640
#define HWp (Hh * Ww)        // 204800
#define NPIX (Bb * HWp)      // 1638400
#define BLK 256

// v4: per-wave MLP via the async global->LDS queue instead of VGPRs.
// v2/v3 tried to hold 24 float4 loads in registers; the compiler re-sank
// them both times (VGPR 36/56, dur unchanged 113us, 1.5 TB/s, both pipes
// idle -> latency-bound). global_load_lds keeps 24 dword loads per wave in
// flight with ZERO register cost; counted vmcnt(20..0) consumes channels
// in order (T4 pattern, m97/m201-verified). 1 px/thread, buf[c][tid] is
// lane-contiguous so the builtin's wave-uniform-base+lane*4 dest rule is
// satisfied. No cross-thread sharing -> no __syncthreads needed.
// LDS 24 KB/block -> 6 blocks/CU = 24 waves/CU, ~6 KB in flight per wave.

template<int N> __device__ __forceinline__ void vm_wait() {
    asm volatile("s_waitcnt vmcnt(%0)" :: "n"(N) : "memory");
}

__global__ __launch_bounds__(BLK) void sparse_regression_kernel(
    const float* __restrict__ cost,
    const float* __restrict__ disp,
    float* __restrict__ pred,   // [B,H,W]   = NPIX floats
    float* __restrict__ prob)   // [B,2,H,W] = 2*NPIX floats
{
    __shared__ float buf[Cc][BLK];   // 24 KB

    const int tid = threadIdx.x;
    const int p   = blockIdx.x * BLK + tid;   // grid is exact: no bounds check
    const int b   = p / HWp;                  // blocks never straddle b (HWp%256==0)
    const int q   = p - b * HWp;              // h*W + w

    const size_t base  = (size_t)b * Cc * HWp + q;
    const float* cbase = cost + base;
    const float* dbase = disp + base;

    // ---- Issue ALL 24 channel loads into the async VMEM->LDS queue.
    // Side-effecting builtins: program order preserved, in-order retirement,
    // no VGPRs consumed by in-flight data. 64 lanes x 4 B = 256 B/instr,
    // fully coalesced. ----
#pragma unroll
    for (int c = 0; c < Cc; ++c) {
        __builtin_amdgcn_global_load_lds(
            (const __attribute__((address_space(1))) void*)(cbase + (size_t)c * HWp),
            (__attribute__((address_space(3))) void*)&buf[c][tid],
            4 /*bytes, literal*/, 0 /*offset*/, 0 /*aux*/);
    }

    float max1 = -INFINITY, max2 = -INFINITY;
    int   idx1 = 0,         idx2 = 0;

    // ---- Consume channels in chunks of 4 with counted per-wave waits.
    // Strict '>' scanning c ascending reproduces lax.top_k's
    // lower-index-wins tie-breaking. buf[c][tid]: consecutive lanes ->
    // consecutive banks, 2 lanes/bank = conflict-free. ----
#define CONSUME4(C0, VM)                                                    \
    vm_wait<VM>();                                                          \
    __builtin_amdgcn_sched_barrier(0);                                      \
    _Pragma("unroll")                                                       \
    for (int c = (C0); c < (C0) + 4; ++c) {                                 \
        const float val = buf[c][tid];                                      \
        const bool gt1 = val > max1;                                        \
        const bool gt2 = val > max2;                                        \
        max2 = gt1 ? max1 : (gt2 ? val : max2);                             \
        idx2 = gt1 ? idx1 : (gt2 ? c   : idx2);                            \
        max1 = gt1 ? val  : max1;                                           \
        idx1 = gt1 ? c    : idx1;                                           \
    }

    CONSUME4(0, 20)
    CONSUME4(4, 16)
    CONSUME4(8, 12)
    CONSUME4(12, 8)
    CONSUME4(16, 4)
    CONSUME4(20, 0)
#undef CONSUME4

    // ---- Gather the two selected disparity samples (data-dependent,
    // per-lane scattered; both issued before either use). ----
    const float d1 = dbase[(size_t)idx1 * HWp];
    const float d2 = dbase[(size_t)idx2 * HWp];

    // softmax over {max1, max2}: p1 = 1/(1+exp(m2-m1)), m2-m1 <= 0
    const float e  = __expf(max2 - max1);
    const float p1 = 1.0f / (1.0f + e);
    const float p2 = 1.0f - p1;

    // Coalesced dword stores (256 B/wave each).
    pred[p] = d1 * p1 + d2 * p2;
    float* pb = prob + (size_t)b * 2 * HWp + q;
    pb[0]   = p1;
    pb[HWp] = p2;
}

extern "C" void kernel_launch(void* const* d_in, const int* in_sizes, int n_in,
                              void* d_out, int out_size, void* d_ws, size_t ws_size,
                              hipStream_t stream) {
    const float* cost = (const float*)d_in[0];
    const float* disp = (const float*)d_in[1];
    float* pred = (float*)d_out;          // first NPIX floats
    float* prob = (float*)d_out + NPIX;   // next 2*NPIX floats

    const int grid = NPIX / BLK;          // 6400, exact
    sparse_regression_kernel<<<grid, BLK, 0, stream>>>(cost, disp, pred, prob);
}